// Round 2
// baseline (17578.790 us; speedup 1.0000x reference)
//
#include <hip/hip_runtime.h>
#include <hip/hip_bf16.h>

#define B_SZ 4096
#define T_SZ 365
#define IN_SZ 32
#define H_SZ 256
#define G4 1024       // 4*H
#define K_SZ 288      // H + IN (K dim of fused gate GEMM)
#define KP 296        // padded LDS row stride
#define M_TILE 64     // batch rows per block
#define NBLK (B_SZ / M_TILE)   // 64
#define NTHR 512      // 8 waves = 2 row-groups x 4 col-groups

typedef __bf16 bf16x8 __attribute__((ext_vector_type(8)));
typedef float f32x4 __attribute__((ext_vector_type(4)));

__device__ __forceinline__ float fast_sigmoid(float x) {
    float e = __builtin_amdgcn_exp2f(-1.4426950408889634f * x);
    return __builtin_amdgcn_rcpf(1.0f + e);
}
__device__ __forceinline__ float fast_tanh(float x) {
    float e = __builtin_amdgcn_exp2f(2.8853900817779268f * x);
    return 1.0f - 2.0f * __builtin_amdgcn_rcpf(1.0f + e);
}

// Pack W = [w_hh | w_ih] as bf16, layout [g][k] (k contiguous) = B^T for MFMA B-frags.
__global__ void pack_w_kernel(const float* __restrict__ w_ih,
                              const float* __restrict__ w_hh,
                              __bf16* __restrict__ wp) {
    int idx = blockIdx.x * 256 + threadIdx.x;
    if (idx >= G4 * K_SZ) return;
    int g = idx / K_SZ, k = idx - g * K_SZ;
    float v = (k < H_SZ) ? w_hh[g * H_SZ + k] : w_ih[g * IN_SZ + (k - H_SZ)];
    wp[idx] = (__bf16)v;
}

__global__ __launch_bounds__(NTHR, 2) void lstm_kernel(
    const float* __restrict__ xd, const float* __restrict__ b,
    const __bf16* __restrict__ wp, const float* __restrict__ w_out,
    const float* __restrict__ b_out, float* __restrict__ out)
{
    // A-operand staging: h (cols 0..255) + x (cols 256..287), split hi/lo bf16
    __shared__ __bf16 a_hi[M_TILE * KP];   // 37.9 KB
    __shared__ __bf16 a_lo[M_TILE * KP];   // 37.9 KB

    const int tid  = threadIdx.x;
    const int wave = tid >> 6;
    const int wc   = wave & 3;       // col-group 0..3
    const int rg   = wave >> 2;      // row-group 0..1 (rg0/rg1 read SAME W frags -> L1 hit)
    const int lane = tid & 63;
    const int quad = lane >> 4;      // 0..3
    const int l16  = lane & 15;      // 0..15
    const int blk  = blockIdx.x;

    for (int i = tid; i < M_TILE * KP; i += NTHR) {
        a_hi[i] = (__bf16)0.f;
        a_lo[i] = (__bf16)0.f;
    }

    // Wave (rg,wc) handles col-tiles T = G*16 + 4*ci + wc (G=gate 0..3, ci=0..3),
    // rows rg*32 + rt*16 + quad*4 + r. h-col j = (wc + 4*ci)*16 + l16.
    float bias[4][4];
#pragma unroll
    for (int G = 0; G < 4; ++G)
#pragma unroll
        for (int ci = 0; ci < 4; ++ci)
            bias[G][ci] = b[G * H_SZ + (wc + 4 * ci) * 16 + l16];

    const f32x4 vzero = {0.f, 0.f, 0.f, 0.f};
    f32x4 creg[2][4];  // [rt][ci]
#pragma unroll
    for (int rt = 0; rt < 2; ++rt)
#pragma unroll
        for (int ci = 0; ci < 4; ++ci) creg[rt][ci] = vzero;

    // x loader: 64 rows x 32 floats = 512 threads x float4
    const int xm = tid >> 3;           // row 0..63
    const int xe = (tid & 7) * 4;      // element 0,4,..,28
    const float* xrow = xd + (size_t)(blk * M_TILE + xm) * (T_SZ * IN_SZ) + xe;
    float4 xv = *(const float4*)xrow;  // t = 0

    // Per-wave W fragment base: row = T*16 + l16, elem offset quad*8 within k-tile
    const __bf16* wb = wp + (size_t)(wc * 16 + l16) * K_SZ + quad * 8;

    for (int t = 0; t < T_SZ; ++t) {
        // stage x_t into LDS (hi/lo split)
        {
            int base = xm * KP + H_SZ + xe;
#pragma unroll
            for (int e = 0; e < 4; ++e) {
                float xf = (&xv.x)[e];
                __bf16 hh = (__bf16)xf;
                a_hi[base + e] = hh;
                a_lo[base + e] = (__bf16)(xf - (float)hh);
            }
        }
        __syncthreads();

        // ---- GEMM: gates[64 x 1024] = [a_hi + a_lo][64 x 288] @ W^T ----
        f32x4 acc[2][16];  // [rt][G*4+ci]
#pragma unroll
        for (int rt = 0; rt < 2; ++rt)
#pragma unroll
            for (int c = 0; c < 16; ++c) acc[rt][c] = vzero;

#pragma unroll
        for (int kt = 0; kt < 9; ++kt) {
            const int k0 = kt * 32 + quad * 8;
            const int r0 = rg * 32;
            bf16x8 ah0 = *(const bf16x8*)&a_hi[(r0 + l16) * KP + k0];
            bf16x8 ah1 = *(const bf16x8*)&a_hi[(r0 + 16 + l16) * KP + k0];
            bf16x8 al0 = *(const bf16x8*)&a_lo[(r0 + l16) * KP + k0];
            bf16x8 al1 = *(const bf16x8*)&a_lo[(r0 + 16 + l16) * KP + k0];
#pragma unroll
            for (int c = 0; c < 16; ++c) {
                // tile T = G*16 + 4*ci + wc, c = G*4 + ci
                const int G = c >> 2, ci = c & 3;
                bf16x8 bf = *(const bf16x8*)(wb + (size_t)((G * 16 + 4 * ci) * 16) * K_SZ + kt * 32);
                acc[0][c] = __builtin_amdgcn_mfma_f32_16x16x32_bf16(ah0, bf, acc[0][c], 0, 0, 0);
                acc[0][c] = __builtin_amdgcn_mfma_f32_16x16x32_bf16(al0, bf, acc[0][c], 0, 0, 0);
                acc[1][c] = __builtin_amdgcn_mfma_f32_16x16x32_bf16(ah1, bf, acc[1][c], 0, 0, 0);
                acc[1][c] = __builtin_amdgcn_mfma_f32_16x16x32_bf16(al1, bf, acc[1][c], 0, 0, 0);
            }
        }
        __syncthreads();  // all waves done reading old h/x before overwrite

        // prefetch next x while doing activation math
        if (t + 1 < T_SZ) xv = *(const float4*)(xrow + (size_t)(t + 1) * IN_SZ);

        // ---- activations + state update (fp32) ----
#pragma unroll
        for (int rt = 0; rt < 2; ++rt) {
#pragma unroll
            for (int ci = 0; ci < 4; ++ci) {
                const int j = (wc + 4 * ci) * 16 + l16;  // h column
                f32x4 ip = acc[rt][0 + ci];
                f32x4 fp = acc[rt][4 + ci];
                f32x4 gp = acc[rt][8 + ci];
                f32x4 op = acc[rt][12 + ci];
#pragma unroll
                for (int r = 0; r < 4; ++r) {
                    float iv = fast_sigmoid(ip[r] + bias[0][ci]);
                    float fv = fast_sigmoid(fp[r] + bias[1][ci]);
                    float gv = fast_tanh(gp[r] + bias[2][ci]);
                    float ov = fast_sigmoid(op[r] + bias[3][ci]);
                    float cv = fv * creg[rt][ci][r] + iv * gv;
                    creg[rt][ci][r] = cv;
                    float hv = ov * fast_tanh(cv);
                    __bf16 hh = (__bf16)hv;
                    const int m = rg * 32 + rt * 16 + quad * 4 + r;
                    a_hi[m * KP + j] = hh;
                    a_lo[m * KP + j] = (__bf16)(hv - (float)hh);
                }
            }
        }
    }
    __syncthreads();

    // ---- epilogue: out[m] = relu(h_T . w_out + b_out) ----
    {
        const int m = tid >> 3;        // row 0..63
        const int p = tid & 7;         // 8 partials per row
        float s = 0.f;
#pragma unroll
        for (int jj = 0; jj < 32; ++jj) {
            int j = p * 32 + jj;
            s += ((float)a_hi[m * KP + j] + (float)a_lo[m * KP + j]) * w_out[j];
        }
        s += __shfl_xor(s, 1);
        s += __shfl_xor(s, 2);
        s += __shfl_xor(s, 4);
        if (p == 0) out[blk * M_TILE + m] = fmaxf(s + b_out[0], 0.f);
    }
}

extern "C" void kernel_launch(void* const* d_in, const int* in_sizes, int n_in,
                              void* d_out, int out_size, void* d_ws, size_t ws_size,
                              hipStream_t stream) {
    const float* xd    = (const float*)d_in[0];
    const float* w_ih  = (const float*)d_in[1];
    const float* w_hh  = (const float*)d_in[2];
    const float* b     = (const float*)d_in[3];
    const float* w_out = (const float*)d_in[4];
    const float* b_out = (const float*)d_in[5];
    float* out = (float*)d_out;

    __bf16* wp = (__bf16*)d_ws;  // 1024*288*2 = 576 KB

    int pack_elems = G4 * K_SZ;
    pack_w_kernel<<<(pack_elems + 255) / 256, 256, 0, stream>>>(w_ih, w_hh, wp);
    lstm_kernel<<<NBLK, NTHR, 0, stream>>>(xd, b, wp, w_out, b_out, out);
}

// Round 3
// 11988.590 us; speedup vs baseline: 1.4663x; 1.4663x over previous
//
#include <hip/hip_runtime.h>
#include <hip/hip_bf16.h>
#include <hip/hip_fp16.h>

#define B_SZ 4096
#define T_SZ 365
#define IN_SZ 32
#define H_SZ 256
#define G4 1024       // 4*H
#define K_SZ 288      // H + IN (K dim of fused gate GEMM)
#define KP 296        // padded LDS row stride (halfs)
#define M_TILE 32     // batch rows per block
#define NBLK (B_SZ / M_TILE)   // 128
#define NTHR 1024     // 16 waves = 2 row-groups x 8 col-groups

typedef _Float16 f16x8 __attribute__((ext_vector_type(8)));
typedef float f32x4 __attribute__((ext_vector_type(4)));

__device__ __forceinline__ float fast_sigmoid(float x) {
    float e = __builtin_amdgcn_exp2f(-1.4426950408889634f * x);
    return __builtin_amdgcn_rcpf(1.0f + e);
}
__device__ __forceinline__ float fast_tanh(float x) {
    float e = __builtin_amdgcn_exp2f(2.8853900817779268f * x);
    return 1.0f - 2.0f * __builtin_amdgcn_rcpf(1.0f + e);
}

// Pack W = [w_hh | w_ih] as fp16, layout [g][k] (k contiguous) = B^T for MFMA B-frags.
__global__ void pack_w_kernel(const float* __restrict__ w_ih,
                              const float* __restrict__ w_hh,
                              _Float16* __restrict__ wp) {
    int idx = blockIdx.x * 256 + threadIdx.x;
    if (idx >= G4 * K_SZ) return;
    int g = idx / K_SZ, k = idx - g * K_SZ;
    float v = (k < H_SZ) ? w_hh[g * H_SZ + k] : w_ih[g * IN_SZ + (k - H_SZ)];
    wp[idx] = (_Float16)v;
}

__global__ __launch_bounds__(NTHR, 1) void lstm_kernel(
    const float* __restrict__ xd, const float* __restrict__ b,
    const _Float16* __restrict__ wp, const float* __restrict__ w_out,
    const float* __restrict__ b_out, float* __restrict__ out)
{
    // A-operand: h (cols 0..255) + x (cols 256..287), single fp16
    __shared__ _Float16 a_s[M_TILE * KP];   // 18.9 KB

    const int tid  = threadIdx.x;
    const int wave = tid >> 6;
    const int cg   = wave & 7;       // col-group 0..7 (owns h-cols cg*32..+32)
    const int rg   = wave >> 3;      // row-group 0..1; (cg,0)/(cg,1) read SAME W -> L1 reuse
    const int lane = tid & 63;
    const int quad = lane >> 4;      // 0..3
    const int l16  = lane & 15;      // 0..15
    const int blk  = blockIdx.x;

    for (int i = tid; i < M_TILE * KP; i += NTHR) a_s[i] = (_Float16)0.f;

    // Wave (rg,cg): col-tiles T = G*16 + cg*2 + ci (G=gate 0..3, ci=0..1),
    // rows rg*16 + quad*4 + r. h-col j = cg*32 + ci*16 + l16.
    float bias[4][2];
#pragma unroll
    for (int G = 0; G < 4; ++G)
#pragma unroll
        for (int ci = 0; ci < 2; ++ci)
            bias[G][ci] = b[G * H_SZ + cg * 32 + ci * 16 + l16];

    const f32x4 vzero = {0.f, 0.f, 0.f, 0.f};
    f32x4 creg[2];
    creg[0] = vzero; creg[1] = vzero;

    // x loader: 32 rows x 32 floats = 1024 threads x 1 float
    const int xm = tid >> 5;           // row 0..31
    const int xe = tid & 31;           // element 0..31
    const float* xrow = xd + (size_t)(blk * M_TILE + xm) * (T_SZ * IN_SZ) + xe;
    float xv = *xrow;                  // t = 0

    // Per-wave W fragment base: row = T*16 + l16, elem offset quad*8 within k-tile
    const _Float16* wb = wp + (size_t)(cg * 32 + l16) * K_SZ + quad * 8;

    for (int t = 0; t < T_SZ; ++t) {
        a_s[xm * KP + H_SZ + xe] = (_Float16)xv;
        __syncthreads();

        // ---- GEMM: gates[32 x 1024] = A[32 x 288] @ W^T ----
        f32x4 acc[8];   // c = G*2 + ci
#pragma unroll
        for (int c = 0; c < 8; ++c) acc[c] = vzero;

#pragma unroll
        for (int kt = 0; kt < 9; ++kt) {
            f16x8 av = *(const f16x8*)&a_s[(rg * 16 + l16) * KP + kt * 32 + quad * 8];
#pragma unroll
            for (int c = 0; c < 8; ++c) {
                const int G = c >> 1, ci = c & 1;
                f16x8 bv = *(const f16x8*)(wb + (size_t)(G * 256 + ci * 16) * K_SZ + kt * 32);
                acc[c] = __builtin_amdgcn_mfma_f32_16x16x32_f16(av, bv, acc[c], 0, 0, 0);
            }
        }
        __syncthreads();  // all waves done reading old h/x before overwrite

        // prefetch next x while doing activation math
        if (t + 1 < T_SZ) xv = xrow[(size_t)(t + 1) * IN_SZ];

        // ---- activations + state update (fp32) ----
#pragma unroll
        for (int ci = 0; ci < 2; ++ci) {
            const int j = cg * 32 + ci * 16 + l16;  // h column
            f32x4 ip = acc[0 + ci];
            f32x4 fp = acc[2 + ci];
            f32x4 gp = acc[4 + ci];
            f32x4 op = acc[6 + ci];
#pragma unroll
            for (int r = 0; r < 4; ++r) {
                float iv = fast_sigmoid(ip[r] + bias[0][ci]);
                float fv = fast_sigmoid(fp[r] + bias[1][ci]);
                float gv = fast_tanh(gp[r] + bias[2][ci]);
                float ov = fast_sigmoid(op[r] + bias[3][ci]);
                float cv = fv * creg[ci][r] + iv * gv;
                creg[ci][r] = cv;
                float hv = ov * fast_tanh(cv);
                const int m = rg * 16 + quad * 4 + r;
                a_s[m * KP + j] = (_Float16)hv;
            }
        }
    }
    __syncthreads();

    // ---- epilogue: out[m] = relu(h_T . w_out + b_out) ----
    {
        const int m = tid >> 5;        // row 0..31
        const int p = tid & 31;        // 32 partials per row (within half-wave)
        float s = 0.f;
#pragma unroll
        for (int jj = 0; jj < 8; ++jj) {
            int j = p * 8 + jj;
            s += (float)a_s[m * KP + j] * w_out[j];
        }
        s += __shfl_xor(s, 1);
        s += __shfl_xor(s, 2);
        s += __shfl_xor(s, 4);
        s += __shfl_xor(s, 8);
        s += __shfl_xor(s, 16);
        if (p == 0) out[blk * M_TILE + m] = fmaxf(s + b_out[0], 0.f);
    }
}

extern "C" void kernel_launch(void* const* d_in, const int* in_sizes, int n_in,
                              void* d_out, int out_size, void* d_ws, size_t ws_size,
                              hipStream_t stream) {
    const float* xd    = (const float*)d_in[0];
    const float* w_ih  = (const float*)d_in[1];
    const float* w_hh  = (const float*)d_in[2];
    const float* b     = (const float*)d_in[3];
    const float* w_out = (const float*)d_in[4];
    const float* b_out = (const float*)d_in[5];
    float* out = (float*)d_out;

    _Float16* wp = (_Float16*)d_ws;  // 1024*288*2 = 576 KB

    int pack_elems = G4 * K_SZ;
    pack_w_kernel<<<(pack_elems + 255) / 256, 256, 0, stream>>>(w_ih, w_hh, wp);
    lstm_kernel<<<NBLK, NTHR, 0, stream>>>(xd, b, wp, w_out, b_out, out);
}

// Round 5
// 3119.407 us; speedup vs baseline: 5.6353x; 3.8432x over previous
//
#include <hip/hip_runtime.h>
#include <hip/hip_fp16.h>

#define T_SZ 365
#define IN_SZ 32
#define H_SZ 256
#define G4 1024
#define K_SZ 288
#define KP 296        // padded LDS row stride (halfs)
#define M_GRP 128     // batch rows per 8-block group
#define N_GRP 32      // groups (32*128 = 4096)
#define Q_PER 8       // blocks per group, each owns 32 h-cols
#define NTHR 512      // 8 waves = 4 m-groups x 2 j-halves
#define NBLK 256      // 1 block per CU, all co-resident (VGPR-gated to 8 waves/CU)

// workspace offsets (bytes)
#define ARR_OFF (640*1024)
#define HX_OFF  (1024*1024)

typedef _Float16 f16x8 __attribute__((ext_vector_type(8)));
typedef float f32x4 __attribute__((ext_vector_type(4)));
typedef unsigned long long u64;

__device__ __forceinline__ float fast_sigmoid(float x) {
    float e = __builtin_amdgcn_exp2f(-1.4426950408889634f * x);
    return __builtin_amdgcn_rcpf(1.0f + e);
}
__device__ __forceinline__ float fast_tanh(float x) {
    float e = __builtin_amdgcn_exp2f(2.8853900817779268f * x);
    return 1.0f - 2.0f * __builtin_amdgcn_rcpf(1.0f + e);
}

// Pack W = [w_hh | w_ih] as fp16, layout [gate-row][k] (k contiguous) = B^T.
__global__ void pack_w_kernel(const float* __restrict__ w_ih,
                              const float* __restrict__ w_hh,
                              _Float16* __restrict__ wp) {
    int idx = blockIdx.x * 256 + threadIdx.x;
    if (idx >= G4 * K_SZ) return;
    int g = idx / K_SZ, k = idx - g * K_SZ;
    float v = (k < H_SZ) ? w_hh[g * H_SZ + k] : w_ih[g * IN_SZ + (k - H_SZ)];
    wp[idx] = (_Float16)v;
}

__global__ void init_sync_kernel(unsigned int* arrive) {
    int i = threadIdx.x;
    if (i < N_GRP) arrive[i * 16] = 0u;   // one counter per 64 B
}

__global__ __launch_bounds__(NTHR, 2) void lstm_kernel(
    const float* __restrict__ xd, const float* __restrict__ b,
    const _Float16* __restrict__ wp, const float* __restrict__ w_out,
    const float* __restrict__ b_out, float* __restrict__ out,
    u64* hx, unsigned int* arrive)
{
    // A-operand: h (cols 0..255, global j) + x (cols 256..287)
    __shared__ _Float16 a_s[M_GRP * KP];   // 75,776 B -> 1 block/CU

    const int tid  = threadIdx.x;
    const int wave = tid >> 6;
    const int mg   = wave >> 1;      // 0..3: owns m-rows [mg*32, +32)
    const int jh   = wave & 1;       // j-half within block slice
    const int lane = tid & 63;
    const int quad = lane >> 4;
    const int l16  = lane & 15;
    const int blk  = blockIdx.x;
    const int q    = blk >> 5;       // group member 0..7: owns j in [q*32, +32)
    const int g    = blk & 31;       // group id

    // ---- W slice (4 gates x 16 j-cols x K=288) entirely into registers: 144 VGPR ----
    f16x8 wfr[4][9];
#pragma unroll
    for (int G = 0; G < 4; ++G) {
        const _Float16* wr = wp + (size_t)(G * 256 + q * 32 + jh * 16 + l16) * K_SZ + quad * 8;
#pragma unroll
        for (int kt = 0; kt < 9; ++kt)
            wfr[G][kt] = *(const f16x8*)(wr + kt * 32);
    }

    float bias[4];
#pragma unroll
    for (int G = 0; G < 4; ++G) bias[G] = b[G * 256 + q * 32 + jh * 16 + l16];

    for (int i = tid; i < M_GRP * KP; i += NTHR) a_s[i] = (_Float16)0.f;

    // x loader: 128 rows x 32 floats; thread owns 8 consecutive floats of one row
    const int mx = tid >> 2;
    const int e0 = (tid & 3) * 8;
    const float* xrow = xd + (size_t)(g * M_GRP + mx) * (T_SZ * IN_SZ) + e0;
    float4 xa = *(const float4*)(xrow);
    float4 xb = *(const float4*)(xrow + 4);

    f32x4 creg[2];
    creg[0] = (f32x4){0.f, 0.f, 0.f, 0.f};
    creg[1] = (f32x4){0.f, 0.f, 0.f, 0.f};

    // stage x_0
    {
        f16x8 xv;
        xv[0]=(_Float16)xa.x; xv[1]=(_Float16)xa.y; xv[2]=(_Float16)xa.z; xv[3]=(_Float16)xa.w;
        xv[4]=(_Float16)xb.x; xv[5]=(_Float16)xb.y; xv[6]=(_Float16)xb.z; xv[7]=(_Float16)xb.w;
        *(f16x8*)&a_s[mx * KP + H_SZ + e0] = xv;
    }
    __syncthreads();

    const _Float16* arow0 = &a_s[(mg * 32 + l16) * KP + quad * 8];
    const _Float16* arow1 = arow0 + 16 * KP;
    const int jcol = q * 32 + jh * 16 + l16;   // this lane's global h column
    unsigned int* arr = &arrive[g * 16];
    unsigned int target = 0;
    const f32x4 vzero = {0.f, 0.f, 0.f, 0.f};

    for (int t = 0; t < T_SZ; ++t) {
        // ---- GEMM: preacts[128 x 128-slice] = A[128 x 288] @ Wslice^T (W in regs) ----
        f32x4 acc[2][4];
#pragma unroll
        for (int mt = 0; mt < 2; ++mt)
#pragma unroll
            for (int G = 0; G < 4; ++G) acc[mt][G] = vzero;

#pragma unroll
        for (int kt = 0; kt < 9; ++kt) {
            f16x8 a0 = *(const f16x8*)(arow0 + kt * 32);
            f16x8 a1 = *(const f16x8*)(arow1 + kt * 32);
#pragma unroll
            for (int G = 0; G < 4; ++G) {
                acc[0][G] = __builtin_amdgcn_mfma_f32_16x16x32_f16(a0, wfr[G][kt], acc[0][G], 0, 0, 0);
                acc[1][G] = __builtin_amdgcn_mfma_f32_16x16x32_f16(a1, wfr[G][kt], acc[1][G], 0, 0, 0);
            }
        }

        // prefetch next x
        if (t + 1 < T_SZ) {
            xa = *(const float4*)(xrow + (size_t)(t + 1) * IN_SZ);
            xb = *(const float4*)(xrow + (size_t)(t + 1) * IN_SZ + 4);
        }

        // ---- activations + state update; h -> own a_s columns ----
#pragma unroll
        for (int mt = 0; mt < 2; ++mt) {
#pragma unroll
            for (int r = 0; r < 4; ++r) {
                float iv = fast_sigmoid(acc[mt][0][r] + bias[0]);
                float fv = fast_sigmoid(acc[mt][1][r] + bias[1]);
                float gv = fast_tanh  (acc[mt][2][r] + bias[2]);
                float ov = fast_sigmoid(acc[mt][3][r] + bias[3]);
                float cv = fv * creg[mt][r] + iv * gv;
                creg[mt][r] = cv;
                float hv = ov * fast_tanh(cv);
                int m = mg * 32 + mt * 16 + quad * 4 + r;
                a_s[m * KP + jcol] = (_Float16)hv;
            }
        }
        __syncthreads();

        // ---- push own slice: member q owns u64 units [q*8, q*8+8) of each 64-unit row ----
        u64* hxg = hx + ((size_t)(t & 1) * N_GRP + g) * (M_GRP * 64);  // [m][64 u64]
#pragma unroll
        for (int i = 0; i < 2; ++i) {
            int u = tid + i * 512;          // 0..1023: m = u>>3, jc = u&7
            int m = u >> 3, jc = u & 7;
            u64 v = *(const u64*)&a_s[m * KP + q * 32 + jc * 4];   // 4 halfs per u64
            __hip_atomic_store(&hxg[(size_t)m * 64 + q * 8 + jc], v,
                               __ATOMIC_RELAXED, __HIP_MEMORY_SCOPE_AGENT);
        }
        asm volatile("s_waitcnt vmcnt(0)" ::: "memory");
        __syncthreads();

        // ---- group barrier: monotonic arrival counter at the coherence point ----
        target += Q_PER;
        if (tid == 0) {
            __hip_atomic_fetch_add(arr, 1u, __ATOMIC_RELEASE, __HIP_MEMORY_SCOPE_AGENT);
            while (__hip_atomic_load(arr, __ATOMIC_ACQUIRE, __HIP_MEMORY_SCOPE_AGENT) < target)
                __builtin_amdgcn_s_sleep(8);
        }
        __syncthreads();

        // ---- pull full h_{t+1} (64 KB) -> a_s ----
        u64 v[16];
#pragma unroll
        for (int i = 0; i < 16; ++i)
            v[i] = __hip_atomic_load(&hxg[tid + i * 512],
                                     __ATOMIC_RELAXED, __HIP_MEMORY_SCOPE_AGENT);
#pragma unroll
        for (int i = 0; i < 16; ++i) {
            int u = tid + i * 512;          // m = u>>6, c = u&63 (u64 unit)
            int m = u >> 6, c = u & 63;
            *(u64*)&a_s[m * KP + c * 4] = v[i];
        }
        // stage x_{t+1}
        if (t + 1 < T_SZ) {
            f16x8 xv;
            xv[0]=(_Float16)xa.x; xv[1]=(_Float16)xa.y; xv[2]=(_Float16)xa.z; xv[3]=(_Float16)xa.w;
            xv[4]=(_Float16)xb.x; xv[5]=(_Float16)xb.y; xv[6]=(_Float16)xb.z; xv[7]=(_Float16)xb.w;
            *(f16x8*)&a_s[mx * KP + H_SZ + e0] = xv;
        }
        __syncthreads();
    }

    // ---- epilogue: out[m] = relu(h_T . w_out + b_out); only member q==0 writes ----
    if (q == 0) {
        const int m = tid >> 2, p = tid & 3;
        float s = 0.f;
#pragma unroll
        for (int jj = 0; jj < 64; ++jj) {
            int j = p * 64 + jj;
            s += (float)a_s[m * KP + j] * w_out[j];
        }
        s += __shfl_xor(s, 1);
        s += __shfl_xor(s, 2);
        if (p == 0) out[(size_t)g * M_GRP + m] = fmaxf(s + b_out[0], 0.f);
    }
}

extern "C" void kernel_launch(void* const* d_in, const int* in_sizes, int n_in,
                              void* d_out, int out_size, void* d_ws, size_t ws_size,
                              hipStream_t stream) {
    const float* xd    = (const float*)d_in[0];
    const float* w_ih  = (const float*)d_in[1];
    const float* w_hh  = (const float*)d_in[2];
    const float* b     = (const float*)d_in[3];
    const float* w_out = (const float*)d_in[4];
    const float* b_out = (const float*)d_in[5];
    float* out = (float*)d_out;

    _Float16* wp = (_Float16*)d_ws;                                 // 576 KB @ 0
    unsigned int* arrive = (unsigned int*)((char*)d_ws + ARR_OFF);  // 2 KB
    u64* hx = (u64*)((char*)d_ws + HX_OFF);                         // 4 MB (double-buffered)

    pack_w_kernel<<<(G4 * K_SZ + 255) / 256, 256, 0, stream>>>(w_ih, w_hh, wp);
    init_sync_kernel<<<1, 64, 0, stream>>>(arrive);
    lstm_kernel<<<NBLK, NTHR, 0, stream>>>(xd, b, wp, w_out, b_out, out, hx, arrive);
}